// Round 2
// baseline (17555.699 us; speedup 1.0000x reference)
//
#include <hip/hip_runtime.h>

typedef unsigned short u16;
typedef unsigned int   u32;
typedef unsigned long long u64;

typedef __attribute__((ext_vector_type(8))) _Float16 half8;
typedef __attribute__((ext_vector_type(4))) float    f32x4;
typedef __attribute__((ext_vector_type(4))) u32      u32x4;

#define T_STEPS 512

// ---------- helpers ----------
__device__ __forceinline__ f32x4 mfma16(u32x4 a, u32x4 b, f32x4 c) {
  union { u32x4 u; half8 h; } A, B;
  A.u = a; B.u = b;
  return __builtin_amdgcn_mfma_f32_16x16x32_f16(A.h, B.h, c, 0, 0, 0);
}
__device__ __forceinline__ u16 f2h(float f) {
  union { _Float16 h; u16 u; } x; x.h = (_Float16)f; return x.u;
}
__device__ __forceinline__ float h2f(u16 v) {
  union { _Float16 h; u16 u; } x; x.u = v; return (float)x.h;
}
__device__ __forceinline__ float sigm(float x)  { return 1.0f / (1.0f + __expf(-x)); }
__device__ __forceinline__ float tanhx(float x) { return 2.0f / (1.0f + __expf(-2.0f * x)) - 1.0f; }

// 16-MFMA matmul: A-frags (regs) x LDS weight slice
__device__ __forceinline__ f32x4 mm(const u32x4* af, const u32x4* lw, int slice, int lane) {
  f32x4 acc = {0.f, 0.f, 0.f, 0.f};
#pragma unroll
  for (int kc = 0; kc < 16; ++kc)
    acc = mfma16(af[kc], lw[slice * 1024 + kc * 64 + lane], acc);
  return acc;
}

// ---- self-validating packet transport ----
// Packet (16B): {u32 d0 (2 fp16), u32 d1 (2 fp16), u32 epoch, u32 pad}. One
// dwordx4 store => tag+data land in one VMEM transaction. Consumer polls the
// packet itself: tag>=want implies the data in the SAME load is the payload.
// Per state: [m 0..63][p 0..63][h 0..1] -> idx m*128 + p*2 + h (u32x4 units).

// poll 32 packets (16 kc x 2 halves) for one A-frag set; selective retry of
// lagging kc slots (wave-uniform), single vmcnt batch per pass.
#define PK_FOREACH(F) \
  F(0, "0", "16")        F(1, "128", "144")     F(2, "256", "272")     F(3, "384", "400")     \
  F(4, "512", "528")     F(5, "640", "656")     F(6, "768", "784")     F(7, "896", "912")     \
  F(8, "1024", "1040")   F(9, "1152", "1168")   F(10, "1280", "1296")  F(11, "1408", "1424")  \
  F(12, "1536", "1552")  F(13, "1664", "1680")  F(14, "1792", "1808")  F(15, "1920", "1936")

__device__ __forceinline__ void poll_frags(u32x4* af, const u32x4* bp, u32 want) {
  u32x4 t0[16], t1[16];
#define PK_LD(k, O0, O1) \
  asm volatile("global_load_dwordx4 %0, %1, off offset:" O0 " sc0 sc1" \
               : "=v"(t0[k]) : "v"(bp) : "memory"); \
  asm volatile("global_load_dwordx4 %0, %1, off offset:" O1 " sc0 sc1" \
               : "=v"(t1[k]) : "v"(bp) : "memory");
#define PK_LAU(k, O0, O1) asm volatile("" : "+v"(t0[k]), "+v"(t1[k]));
#define PK_CHK(k, O0, O1) \
  if (__any((int)((t0[k].z < want) || (t1[k].z < want)))) { PK_LD(k, O0, O1) nd = 1; }
  PK_FOREACH(PK_LD)
  asm volatile("s_waitcnt vmcnt(0)" ::: "memory");
  PK_FOREACH(PK_LAU)
  for (;;) {
    int nd = 0;
    PK_FOREACH(PK_CHK)
    if (!nd) break;
    asm volatile("s_waitcnt vmcnt(0)" ::: "memory");
    PK_FOREACH(PK_LAU)
  }
#pragma unroll
  for (int k = 0; k < 16; ++k) {
    af[k].x = t0[k].x; af[k].y = t0[k].y;
    af[k].z = t1[k].x; af[k].w = t1[k].y;
  }
#undef PK_LD
#undef PK_LAU
#undef PK_CHK
}

// emit a [16 x 8] fp16 tile as 32 packets. v[i] valid on lanes with n<8
// (rows r0+i, col n). LDS transpose via per-wave scratch (in-order DS per
// wave => no barrier), lgkm drain also publishes any scr_* f32 LDS writes
// made before this call (consumers are gated by the packet tags).
__device__ __forceinline__ void pkt_emit(u32x4* sbase, u16* scrw, int lane, int mrow0,
                                         int jb, u32 ep, const float* v) {
  const int n = lane & 15;
  const int r0 = (lane >> 4) * 4;
  if (n < 8) {
#pragma unroll
    for (int i = 0; i < 4; ++i) scrw[(r0 + i) * 8 + n] = f2h(v[i]);
  }
  asm volatile("s_waitcnt lgkmcnt(0)" ::: "memory");
  __builtin_amdgcn_sched_barrier(0);
  if (n < 8) {
    const int q = (lane >> 4) * 8 + n;
    const int r = q >> 1, hh = q & 1;
    const u32* d = (const u32*)(scrw + r * 8 + hh * 4);
    u32x4 pk;
    pk.x = d[0]; pk.y = d[1]; pk.z = ep; pk.w = 0u;
    u32x4* addr = sbase + ((mrow0 + r) * 128 + jb * 2 + hh);
    asm volatile("global_store_dwordx4 %0, %1, off sc0 sc1" :: "v"(addr), "v"(pk) : "memory");
  }
}

// ---------- prelude 1: pack weights (f32 -> fp16) into MFMA B-fragment lane order ----------
__global__ __launch_bounds__(256) void pack_kernel(const float* __restrict__ w0,
                                                   const float* __restrict__ wsrc,
                                                   u16* __restrict__ wp) {
  int gid = blockIdx.x * 256 + threadIdx.x;  // < 655360
  int w = gid >> 16, c = gid & 65535;
  int jb = c >> 10, kc = (c >> 6) & 15, lane = c & 63;
  int nl = lane & 15, kh = lane >> 4;
  int n = (nl < 8) ? (jb * 8 + nl) : (512 + jb * 8 + nl - 8);
  int k = kc * 32 + kh * 8;
  const float* s;
  if (w == 0)      s = w0 + (size_t)k * 1024 + n;
  else if (w == 1) s = w0 + (size_t)(512 + k) * 1024 + n;
  else             s = wsrc + (size_t)(w - 2) * 524288 + (size_t)k * 1024 + n;
  u32 e[8];
#pragma unroll
  for (int i = 0; i < 8; ++i) e[i] = (u32)f2h(s[(size_t)i * 1024]);
  uint4 v;
  v.x = e[0] | (e[1] << 16); v.y = e[2] | (e[3] << 16);
  v.z = e[4] | (e[5] << 16); v.w = e[6] | (e[7] << 16);
  ((uint4*)wp)[gid] = v;
}

// ---------- prelude 2: XW = x[t] @ W0x, stored PACKED in C-frag layout ----------
__global__ __launch_bounds__(256) void xw_kernel(const float* __restrict__ x,
                                                 const u16* __restrict__ wp,
                                                 u64* __restrict__ xwp) {
  __shared__ uint4 smem[4096];  // 64KB: full x[t] in A-frag layout
  int t = blockIdx.x >> 4, jbg = blockIdx.x & 15;
  int tid = threadIdx.x, lane = tid & 63, wv = tid >> 6;
  const float* src = x + (size_t)t * 64 * 512;
#pragma unroll
  for (int it = 0; it < 16; ++it) {
    int d = tid + it * 256;
    int ln = d & 63, kcL = (d >> 6) & 15, mtL = d >> 10;
    int lm = mtL * 16 + (ln & 15);
    int k8 = kcL * 4 + (ln >> 4);
    const float* p = src + (size_t)lm * 512 + (size_t)k8 * 8;
    float4 a = *(const float4*)p;
    float4 b = *(const float4*)(p + 4);
    uint4 v;
    v.x = (u32)f2h(a.x) | ((u32)f2h(a.y) << 16);
    v.y = (u32)f2h(a.z) | ((u32)f2h(a.w) << 16);
    v.z = (u32)f2h(b.x) | ((u32)f2h(b.y) << 16);
    v.w = (u32)f2h(b.z) | ((u32)f2h(b.w) << 16);
    smem[d] = v;
  }
  __syncthreads();
  int jb = jbg * 4 + wv;
  const uint4* bp = (const uint4*)wp + (size_t)jb * 1024;  // pack 0 = W0x
  f32x4 acc[4] = {{0,0,0,0},{0,0,0,0},{0,0,0,0},{0,0,0,0}};
#pragma unroll
  for (int kc = 0; kc < 16; ++kc) {
    uint4 b = bp[kc * 64 + lane];
    union { uint4 u; half8 h; } B; B.u = b;
#pragma unroll
    for (int m4 = 0; m4 < 4; ++m4) {
      union { uint4 u; half8 h; } A; A.u = smem[(m4 * 16 + kc) * 64 + lane];
      acc[m4] = __builtin_amdgcn_mfma_f32_16x16x32_f16(A.h, B.h, acc[m4], 0, 0, 0);
    }
  }
#pragma unroll
  for (int m4 = 0; m4 < 4; ++m4) {
    u32 lo = (u32)f2h(acc[m4][0]) | ((u32)f2h(acc[m4][1]) << 16);
    u32 hi = (u32)f2h(acc[m4][2]) | ((u32)f2h(acc[m4][3]) << 16);
    xwp[((size_t)(t * 64 + jb) * 4 + m4) * 64 + lane] = (u64)lo | ((u64)hi << 32);
  }
}

// ---------- prelude 3: h_in -> h packets (state 5), tag 0 ----------
__global__ __launch_bounds__(256) void init_hp(const float* __restrict__ h,
                                               u32x4* __restrict__ pkt) {
  int i = blockIdx.x * 256 + threadIdx.x;  // < 8192
  int m = i >> 7, rest = i & 127;          // rest = p*2 + half
  int col = (rest >> 1) * 8 + (rest & 1) * 4;
  const float* s = h + (size_t)m * 512 + col;
  u32x4 pk;
  pk.x = (u32)f2h(s[0]) | ((u32)f2h(s[1]) << 16);
  pk.y = (u32)f2h(s[2]) | ((u32)f2h(s[3]) << 16);
  pk.z = 0u; pk.w = 0u;
  pkt[(size_t)5 * 8192 + i] = pk;
}

// ---------- persistent recurrence: packet dataflow, zero flags, zero drains ----------
// 128 wgs: jb = wg&63 (cols jb*8..+8), g = wg>>6 (rows g*32..+32). 4 waves:
// mt = wid&1 (16-row tile), sel = wid>>1 (role). Per link: producer emits
// self-tagged packets (no vmcnt drain, no flag); consumer polls packets
// directly (detect == fetch). WAR across epochs is transitively ordered by
// the tag chain s0->s1/s2->s3..s6->h plus the intra-wg lflag handoff.
__global__ __launch_bounds__(256, 1) void recur_kernel(
    const u64* __restrict__ xwp, const float* __restrict__ h_in,
    const u16* __restrict__ wp, u32x4* __restrict__ pkt,
    float* __restrict__ out) {
  extern __shared__ char smem_raw[];
  u32x4* lw     = (u32x4*)smem_raw;                 // [9][16][64] u32x4 = 147456B
  float* scr_s0 = (float*)(smem_raw + 147456);      // [256] f32
  float* scr_s4 = (float*)(smem_raw + 148480);      // [256]
  float* scr_m1 = (float*)(smem_raw + 149504);      // [256]
  u16*   scrw   = (u16*)(smem_raw + 150528);        // [4][128] u16 transpose scratch
  u32*   lflag  = (u32*)(smem_raw + 151552);        // [2]

  const int wg = blockIdx.x;
  const int jb = wg & 63, g = wg >> 6;
  const int tid = threadIdx.x;
  const int lane = tid & 63;
  const int wid = tid >> 6;
  const int mt = wid & 1, sel = wid >> 1;
  const int n = lane & 15, r0 = (lane >> 4) * 4;
  const int mrow0 = g * 32 + mt * 16;
  const int mbase = (mrow0 + n) * 128 + (lane >> 4) * 2;
  const int jj = jb * 8 + (n & 7);
  const int sbase = (mt * 16 + r0) * 8 + (n & 7);
  u16* myscrw = scrw + wid * 128;
  const u32x4* wp4 = (const u32x4*)wp;

  // preload all 9 weight jb-slices into LDS (slice s = pack 1+s)
  for (int idx = tid; idx < 9216; idx += 256) {
    int s = idx >> 10, rem = idx & 1023;
    lw[idx] = wp4[(size_t)(1 + s) * 65536 + (size_t)jb * 1024 + rem];
  }
  if (tid < 2) lflag[tid] = 0;
  __syncthreads();

  float h_reg[4];
  float mean[4] = {0, 0, 0, 0};
  float s0r[4], s1r[4], s3r[4];
  u64 xv = 0;
  if (sel == 0)
    xv = xwp[((size_t)(0 * 64 + jb) * 4 + (g * 2 + mt)) * 64 + lane];

  u32x4 af[16];
  for (int t = 0; t < T_STEPS; ++t) {
    const u32 ep = (u32)t + 1;
    if (sel == 0) {
      // ---------- stage A: s0 = gate(XW[t] + h @ W0h) ----------
      poll_frags(af, pkt + (size_t)5 * 8192 + mbase, (u32)t);
      f32x4 acc = mm(af, lw, 0, lane);
      float v[4], part[4], s0v[4];
#pragma unroll
      for (int i = 0; i < 4; ++i) v[i] = acc[i] + h2f((u16)(xv >> (16 * i)));
#pragma unroll
      for (int i = 0; i < 4; ++i) part[i] = __shfl_xor(v[i], 8);
      if (n < 8) {
#pragma unroll
        for (int i = 0; i < 4; ++i) {
          float hp = (t == 0) ? h_in[(size_t)(mrow0 + r0 + i) * 512 + jj] : h_reg[i];
          float s0 = hp + sigm(v[i]) * (tanhx(part[i]) - hp);
          s0v[i] = s0; s0r[i] = s0;
          scr_s0[sbase + i * 8] = s0;   // drained by pkt_emit's lgkm wait
        }
      }
      pkt_emit(pkt, myscrw, lane, mrow0, jb, ep, s0v);
      int tn = (t < T_STEPS - 1) ? t + 1 : t;   // register prefetch of next XW
      xv = xwp[((size_t)(tn * 64 + jb) * 4 + (g * 2 + mt)) * 64 + lane];
    }
    // ---------- stage B: s1 = tanh-step(s0) [sel0], s2 = relu-step(s0) [sel1] ----------
    poll_frags(af, pkt + mbase, ep);
    {
      f32x4 acc = mm(af, lw, 1 + sel, lane);
      float part[4], sv[4];
#pragma unroll
      for (int i = 0; i < 4; ++i) part[i] = __shfl_xor(acc[i], 8);
      if (n < 8) {
#pragma unroll
        for (int i = 0; i < 4; ++i) {
          float sp = (sel == 0) ? s0r[i] : scr_s0[sbase + i * 8];
          float hc = (sel == 0) ? tanhx(part[i]) : fmaxf(part[i], 0.f);
          float sn = sp + sigm(acc[i]) * (hc - sp);
          s1r[i] = sn; mean[i] = sn; sv[i] = sn;
        }
      }
      pkt_emit(pkt + (size_t)(1 + sel) * 8192, myscrw, lane, mrow0, jb, ep, sv);
    }
    // ---------- stage C: sel0: s3,s4 from s1 ; sel1: s5,s6 from s2 (mean-only) ----------
    poll_frags(af, pkt + (size_t)(1 + sel) * 8192 + mbase, ep);
    {
      f32x4 a0 = {0, 0, 0, 0}, a1 = {0, 0, 0, 0};
#pragma unroll
      for (int kc = 0; kc < 16; ++kc) {
        u32x4 a = af[kc];
        a0 = mfma16(a, lw[(3 + 2 * sel) * 1024 + kc * 64 + lane], a0);
        a1 = mfma16(a, lw[(4 + 2 * sel) * 1024 + kc * 64 + lane], a1);
      }
      float p0[4], p1[4];
#pragma unroll
      for (int i = 0; i < 4; ++i) { p0[i] = __shfl_xor(a0[i], 8); p1[i] = __shfl_xor(a1[i], 8); }
      if (sel == 0) {
        float s3v[4], s4v[4];
        if (n < 8) {
#pragma unroll
          for (int i = 0; i < 4; ++i) {
            float sp = s1r[i];
            float s3 = sp + sigm(a0[i]) * (sigm(p0[i]) - sp);        // step2: sigmoid
            float s4 = sp + sigm(a1[i]) * (p1[i] - sp);              // step3: identity
            mean[i] += s3 + s4;
            s3r[i] = s3;
            s3v[i] = s3; s4v[i] = s4;
            scr_s4[sbase + i * 8] = s4;  // drained by pkt_emit's lgkm wait
          }
        }
        pkt_emit(pkt + (size_t)3 * 8192, myscrw, lane, mrow0, jb, ep, s3v);
        pkt_emit(pkt + (size_t)4 * 8192, myscrw, lane, mrow0, jb, ep, s4v);
      } else {
        if (n < 8) {
#pragma unroll
          for (int i = 0; i < 4; ++i) {
            float sp = s1r[i];
            float s5 = sp + sigm(a0[i]) * (tanhx(p0[i]) - sp);       // step4: tanh
            float s6 = sp + sigm(a1[i]) * (fmaxf(p1[i], 0.f) - sp);  // step5: relu
            mean[i] += s5 + s6;
          }
        }
      }
    }
    // ---------- stage D: sel0: s7 from s3 ; sel1: s8 from s4 ; h = mean/8 ----------
    poll_frags(af, pkt + (size_t)(3 + sel) * 8192 + mbase, ep);
    {
      f32x4 acc = mm(af, lw, 7 + sel, lane);
      float part[4];
#pragma unroll
      for (int i = 0; i < 4; ++i) part[i] = __shfl_xor(acc[i], 8);
      if (sel == 1) {
        if (n < 8) {
#pragma unroll
          for (int i = 0; i < 4; ++i) {
            float sp = scr_s4[sbase + i * 8];
            float s8 = sp + sigm(acc[i]) * (part[i] - sp);           // step7: identity
            scr_m1[sbase + i * 8] = mean[i] + s8;
          }
        }
        asm volatile("s_waitcnt lgkmcnt(0)" ::: "memory");
        if (lane == 0)
          __hip_atomic_store(&lflag[mt], ep, __ATOMIC_RELAXED, __HIP_MEMORY_SCOPE_WORKGROUP);
      } else {
        while (__hip_atomic_load(&lflag[mt], __ATOMIC_RELAXED,
                                 __HIP_MEMORY_SCOPE_WORKGROUP) < ep) {}
        asm volatile("" ::: "memory");
        float hv[4];
        if (n < 8) {
#pragma unroll
          for (int i = 0; i < 4; ++i) {
            int m = mrow0 + r0 + i;
            float s7 = s3r[i] + sigm(acc[i]) * (sigm(part[i]) - s3r[i]);  // step6: sigmoid
            float hn = (mean[i] + s7 + scr_m1[sbase + i * 8]) * 0.125f;
            h_reg[i] = hn; hv[i] = hn;
            out[((size_t)t * 64 + m) * 512 + jj] = hn;
            if (t == T_STEPS - 1) out[(size_t)T_STEPS * 64 * 512 + (size_t)m * 512 + jj] = hn;
          }
        }
        pkt_emit(pkt + (size_t)5 * 8192, myscrw, lane, mrow0, jb, ep, hv);
      }
    }
  }
}

extern "C" void kernel_launch(void* const* d_in, const int* in_sizes, int n_in,
                              void* d_out, int out_size, void* d_ws, size_t ws_size,
                              hipStream_t stream) {
  const float* x_in = (const float*)d_in[0];  // [512,64,512] f32
  const float* h_in = (const float*)d_in[1];  // [1,64,512]  f32
  const float* w0   = (const float*)d_in[2];  // [1024,1024] f32
  const float* wsrc = (const float*)d_in[3];  // [8,512,1024] f32
  float* out = (float*)d_out;
  char* ws = (char*)d_ws;

  // pkt region (768KB, 6 states x 8192 u32x4) aliases wp pack0 (W0x, 1MB):
  // pack0 is consumed only by xw_kernel, which runs BEFORE the pkt memset.
  const size_t O_WP  = 0;                       // 10 MB packed fp16 weights
  const size_t O_XWP = 10485760;                // 64 MB packed XW (u64 frags)
  const size_t NEED  = O_XWP + 67108864;        // ~74.0 MB
  if (ws_size < NEED) return;

  u16*   wp  = (u16*)(ws + O_WP);
  u32x4* pkt = (u32x4*)(ws + O_WP);             // aliases pack0
  u64*   xwp = (u64*)(ws + O_XWP);

  const int LDS_BYTES = 151568;  // 147456 weights + scr + scrw + lflag
  hipFuncSetAttribute((const void*)recur_kernel,
                      hipFuncAttributeMaxDynamicSharedMemorySize, LDS_BYTES);

  pack_kernel<<<dim3(2560), dim3(256), 0, stream>>>(w0, wsrc, wp);
  xw_kernel<<<dim3(8192), dim3(256), 0, stream>>>(x_in, wp, xwp);
  hipMemsetAsync(pkt, 0, 786432, stream);  // zero all packet tags (after xw!)
  init_hp<<<dim3(32), dim3(256), 0, stream>>>(h_in, pkt);
  recur_kernel<<<dim3(128), dim3(256), LDS_BYTES, stream>>>(xwp, h_in, wp, pkt, out);
}

// Round 3
// 13044.730 us; speedup vs baseline: 1.3458x; 1.3458x over previous
//
#include <hip/hip_runtime.h>

typedef unsigned short u16;
typedef unsigned int   u32;
typedef unsigned long long u64;

typedef __attribute__((ext_vector_type(8))) _Float16 half8;
typedef __attribute__((ext_vector_type(4))) float    f32x4;
typedef __attribute__((ext_vector_type(4))) u32      u32x4;

#define T_STEPS 512

// ---------- helpers ----------
__device__ __forceinline__ f32x4 mfma16(u32x4 a, u32x4 b, f32x4 c) {
  union { u32x4 u; half8 h; } A, B;
  A.u = a; B.u = b;
  return __builtin_amdgcn_mfma_f32_16x16x32_f16(A.h, B.h, c, 0, 0, 0);
}
__device__ __forceinline__ u16 f2h(float f) {
  union { _Float16 h; u16 u; } x; x.h = (_Float16)f; return x.u;
}
__device__ __forceinline__ float h2f(u16 v) {
  union { _Float16 h; u16 u; } x; x.u = v; return (float)x.h;
}
__device__ __forceinline__ float sigm(float x)  { return 1.0f / (1.0f + __expf(-x)); }
__device__ __forceinline__ float tanhx(float x) { return 2.0f / (1.0f + __expf(-2.0f * x)) - 1.0f; }

// 16-MFMA matmul: A-frags (regs) x LDS weight slice
__device__ __forceinline__ f32x4 mm(const u32x4* af, const u32x4* lw, int slice, int lane) {
  f32x4 acc = {0.f, 0.f, 0.f, 0.f};
#pragma unroll
  for (int kc = 0; kc < 16; ++kc)
    acc = mfma16(af[kc], lw[slice * 1024 + kc * 64 + lane], acc);
  return acc;
}

// ---- counter-based dataflow sync ----
// Per channel: 8 accumulating u32 counters, 64B apart. 64 producers/channel,
// producer jb adds 1 to counter jb>>3 per epoch (after vmcnt/lgkm drain, no
// cache-maintenance fences). Epoch e complete <=> every counter >= 8*e.
// Consumer: 64 lanes poll the 8 lines (lane&7) -> 8 transactions per pass.
__device__ __forceinline__ void sig(u32* slot) {
  asm volatile("s_waitcnt vmcnt(0) lgkmcnt(0)" ::: "memory");
  if ((threadIdx.x & 63) == 0)
    __hip_atomic_fetch_add(slot, 1u, __ATOMIC_RELAXED, __HIP_MEMORY_SCOPE_AGENT);
}
__device__ __forceinline__ void ctr_wait(const u32* ch, u32 target) {
  const u32* p = ch + (size_t)(threadIdx.x & 7) * 16;
  while (!__all((int)(__hip_atomic_load(p, __ATOMIC_RELAXED,
                                        __HIP_MEMORY_SCOPE_AGENT) >= target))) {}
  asm volatile("" ::: "memory");
}

// ---- gather: 16 rows x 64B of one state tile as 16 dwordx4 agent loads ----
#define FG(k, OFF) \
  asm volatile("global_load_dwordx4 %0, %1, off offset:" OFF " sc0 sc1" \
               : "=v"(af[k]) : "v"(base));
__device__ __forceinline__ void frag_gather(u32x4* af, const u16* buf, int rowoff) {
  const char* base = (const char*)(buf + rowoff);
  FG(0, "0")    FG(1, "64")   FG(2, "128")  FG(3, "192")
  FG(4, "256")  FG(5, "320")  FG(6, "384")  FG(7, "448")
  FG(8, "512")  FG(9, "576")  FG(10, "640") FG(11, "704")
  FG(12, "768") FG(13, "832") FG(14, "896") FG(15, "960")
  asm volatile("s_waitcnt vmcnt(0)" ::: "memory");
  __builtin_amdgcn_sched_barrier(0);   // rule 18: keep MFMA below the wait
}
#undef FG

// ---- emit: per-wave LDS transpose -> ONE coalesced global_store_dword ----
// v[0..3] valid on lanes n<8 (rows r0+i, col n). Produces row-major 16B/row.
// The lgkm drain also publishes any scr_* LDS writes made before this call.
__device__ __forceinline__ void emit_state(u16* dst, u16* sw, int lane, int mrow0,
                                           int jb, const float* v) {
  const int n = lane & 15, rg = (lane >> 4) * 4;
  if (n < 8) {
#pragma unroll
    for (int i = 0; i < 4; ++i) sw[(rg + i) * 8 + n] = f2h(v[i]);
  }
  asm volatile("s_waitcnt lgkmcnt(0)" ::: "memory");
  __builtin_amdgcn_sched_barrier(0);
  u32 w = ((const u32*)sw)[lane];
  u16* addr = dst + (size_t)(mrow0 + (lane >> 2)) * 512 + jb * 8 + (lane & 3) * 2;
  asm volatile("global_store_dword %0, %1, off sc0 sc1" :: "v"(addr), "v"(w) : "memory");
}

// ---------- prelude 1: pack weights (f32 -> fp16) into MFMA B-fragment lane order ----------
__global__ __launch_bounds__(256) void pack_kernel(const float* __restrict__ w0,
                                                   const float* __restrict__ wsrc,
                                                   u16* __restrict__ wp) {
  int gid = blockIdx.x * 256 + threadIdx.x;  // < 655360
  int w = gid >> 16, c = gid & 65535;
  int jb = c >> 10, kc = (c >> 6) & 15, lane = c & 63;
  int nl = lane & 15, kh = lane >> 4;
  int n = (nl < 8) ? (jb * 8 + nl) : (512 + jb * 8 + nl - 8);
  int k = kc * 32 + kh * 8;
  const float* s;
  if (w == 0)      s = w0 + (size_t)k * 1024 + n;
  else if (w == 1) s = w0 + (size_t)(512 + k) * 1024 + n;
  else             s = wsrc + (size_t)(w - 2) * 524288 + (size_t)k * 1024 + n;
  u32 e[8];
#pragma unroll
  for (int i = 0; i < 8; ++i) e[i] = (u32)f2h(s[(size_t)i * 1024]);
  uint4 v;
  v.x = e[0] | (e[1] << 16); v.y = e[2] | (e[3] << 16);
  v.z = e[4] | (e[5] << 16); v.w = e[6] | (e[7] << 16);
  ((uint4*)wp)[gid] = v;
}

// ---------- prelude 2: XW = x[t] @ W0x, stored PACKED in C-frag layout ----------
__global__ __launch_bounds__(256) void xw_kernel(const float* __restrict__ x,
                                                 const u16* __restrict__ wp,
                                                 u64* __restrict__ xwp) {
  __shared__ uint4 smem[4096];  // 64KB: full x[t] in A-frag layout
  int t = blockIdx.x >> 4, jbg = blockIdx.x & 15;
  int tid = threadIdx.x, lane = tid & 63, wv = tid >> 6;
  const float* src = x + (size_t)t * 64 * 512;
#pragma unroll
  for (int it = 0; it < 16; ++it) {
    int d = tid + it * 256;
    int ln = d & 63, kcL = (d >> 6) & 15, mtL = d >> 10;
    int lm = mtL * 16 + (ln & 15);
    int k8 = kcL * 4 + (ln >> 4);
    const float* p = src + (size_t)lm * 512 + (size_t)k8 * 8;
    float4 a = *(const float4*)p;
    float4 b = *(const float4*)(p + 4);
    uint4 v;
    v.x = (u32)f2h(a.x) | ((u32)f2h(a.y) << 16);
    v.y = (u32)f2h(a.z) | ((u32)f2h(a.w) << 16);
    v.z = (u32)f2h(b.x) | ((u32)f2h(b.y) << 16);
    v.w = (u32)f2h(b.z) | ((u32)f2h(b.w) << 16);
    smem[d] = v;
  }
  __syncthreads();
  int jb = jbg * 4 + wv;
  const uint4* bp = (const uint4*)wp + (size_t)jb * 1024;  // pack 0 = W0x
  f32x4 acc[4] = {{0,0,0,0},{0,0,0,0},{0,0,0,0},{0,0,0,0}};
#pragma unroll
  for (int kc = 0; kc < 16; ++kc) {
    union { uint4 u; half8 h; } B; B.u = bp[kc * 64 + lane];
#pragma unroll
    for (int m4 = 0; m4 < 4; ++m4) {
      union { uint4 u; half8 h; } A; A.u = smem[(m4 * 16 + kc) * 64 + lane];
      acc[m4] = __builtin_amdgcn_mfma_f32_16x16x32_f16(A.h, B.h, acc[m4], 0, 0, 0);
    }
  }
#pragma unroll
  for (int m4 = 0; m4 < 4; ++m4) {
    u32 lo = (u32)f2h(acc[m4][0]) | ((u32)f2h(acc[m4][1]) << 16);
    u32 hi = (u32)f2h(acc[m4][2]) | ((u32)f2h(acc[m4][3]) << 16);
    xwp[((size_t)(t * 64 + jb) * 4 + m4) * 64 + lane] = (u64)lo | ((u64)hi << 32);
  }
}

// ---------- prelude 3: fp16 mirror of h_in ----------
__global__ __launch_bounds__(256) void init_hh(const float* __restrict__ h, u16* __restrict__ hh) {
  int i = blockIdx.x * 256 + threadIdx.x;
  if (i < 32768) hh[i] = f2h(h[i]);
}

// ---------- persistent recurrence: counter dataflow, coalesced emit, x4 gather ----------
// 128 wgs: jb = wg&63 (cols jb*8..+8), g = wg>>6 (rows g*32..+32). 4 waves:
// mt = wid&1 (16-row tile), sel = wid>>1 (role). Channels per g: 0+mt: A(s0),
// 2+2*sel+mt: B(s1/s2), 6+mt: C(s3&s4, by sel0), 8+mt: D(h, by sel0).
__global__ __launch_bounds__(256, 1) void recur_kernel(
    const u64* __restrict__ xwp, const float* __restrict__ h_in,
    const u16* __restrict__ wp,
    u16* __restrict__ sh,   // s0..s4 fp16 [5][64][512]
    u16* __restrict__ hh,   // h fp16 [64][512]
    u32* __restrict__ bar,
    float* __restrict__ out) {
  extern __shared__ char smem_raw[];
  u32x4* lw     = (u32x4*)smem_raw;                 // [9][16][64] u32x4 = 147456B
  float* scr_s0 = (float*)(smem_raw + 147456);      // [256] f32
  float* scr_s4 = (float*)(smem_raw + 148480);      // [256]
  float* scr_m1 = (float*)(smem_raw + 149504);      // [256]
  u16*   scrw   = (u16*)(smem_raw + 150528);        // [4 waves][2][128] u16
  u32*   lflag  = (u32*)(smem_raw + 152576);        // [2]

  const int wg = blockIdx.x;
  const int jb = wg & 63, g = wg >> 6;
  const int tid = threadIdx.x;
  const int lane = tid & 63;
  const int wid = tid >> 6;
  const int mt = wid & 1, sel = wid >> 1;
  const int n = lane & 15, r0 = (lane >> 4) * 4;
  const int mrow0 = g * 32 + mt * 16;
  const int rowoff = (mrow0 + n) * 512 + (lane >> 4) * 8;  // fp16 elems
  const int jj = jb * 8 + (n & 7);
  const int sbase = (mt * 16 + r0) * 8 + (n & 7);
  u16* sw0 = scrw + wid * 256;
  u16* sw1 = sw0 + 128;
  const u32x4* wp4 = (const u32x4*)wp;

  u32* flg  = bar + (size_t)g * 1280;               // 10 ch x 128 u32 (512B each)
  u32* chA  = flg + (0 + mt) * 128;
  u32* chB  = flg + (2 + 2 * sel + mt) * 128;
  u32* chC  = flg + (6 + mt) * 128;
  u32* chD  = flg + (8 + mt) * 128;
  u32* chA_s = chA + (jb >> 3) * 16;
  u32* chB_s = chB + (jb >> 3) * 16;
  u32* chC_s = chC + (jb >> 3) * 16;
  u32* chD_s = chD + (jb >> 3) * 16;

  // preload all 9 weight jb-slices into LDS (slice s = pack 1+s)
  for (int idx = tid; idx < 9216; idx += 256) {
    int s = idx >> 10, rem = idx & 1023;
    lw[idx] = wp4[(size_t)(1 + s) * 65536 + (size_t)jb * 1024 + rem];
  }
  if (tid < 2) lflag[tid] = 0;
  __syncthreads();

  float h_reg[4];
  float mean[4] = {0, 0, 0, 0};
  float s0r[4], s1r[4], s3r[4];
  u64 xv = 0;
  if (sel == 0)
    xv = xwp[((size_t)(0 * 64 + jb) * 4 + (g * 2 + mt)) * 64 + lane];

  u32x4 af[16];
  for (int t = 0; t < T_STEPS; ++t) {
    const u32 ep = (u32)t + 1;
    if (sel == 0) {
      // ---------- stage A: s0 = gate(XW[t] + h @ W0h) ----------
      ctr_wait(chD, 8u * (u32)t);
      frag_gather(af, hh, rowoff);
      f32x4 acc = mm(af, lw, 0, lane);
      float v[4], part[4], s0v[4];
#pragma unroll
      for (int i = 0; i < 4; ++i) v[i] = acc[i] + h2f((u16)(xv >> (16 * i)));
#pragma unroll
      for (int i = 0; i < 4; ++i) part[i] = __shfl_xor(v[i], 8);
      if (n < 8) {
#pragma unroll
        for (int i = 0; i < 4; ++i) {
          float hp = (t == 0) ? h_in[(size_t)(mrow0 + r0 + i) * 512 + jj] : h_reg[i];
          float s0 = hp + sigm(v[i]) * (tanhx(part[i]) - hp);
          s0v[i] = s0; s0r[i] = s0;
          scr_s0[sbase + i * 8] = s0;   // drained by emit's lgkm wait
        }
      }
      emit_state(sh, sw0, lane, mrow0, jb, s0v);
      sig(chA_s);
      int tn = (t < T_STEPS - 1) ? t + 1 : t;   // register prefetch of next XW
      xv = xwp[((size_t)(tn * 64 + jb) * 4 + (g * 2 + mt)) * 64 + lane];
    }
    // ---------- stage B: s1 = tanh-step(s0) [sel0], s2 = relu-step(s0) [sel1] ----------
    ctr_wait(chA, 8u * ep);
    frag_gather(af, sh, rowoff);
    {
      f32x4 acc = mm(af, lw, 1 + sel, lane);
      float part[4], sv[4];
#pragma unroll
      for (int i = 0; i < 4; ++i) part[i] = __shfl_xor(acc[i], 8);
      if (n < 8) {
#pragma unroll
        for (int i = 0; i < 4; ++i) {
          float sp = (sel == 0) ? s0r[i] : scr_s0[sbase + i * 8];
          float hc = (sel == 0) ? tanhx(part[i]) : fmaxf(part[i], 0.f);
          float sn = sp + sigm(acc[i]) * (hc - sp);
          s1r[i] = sn; mean[i] = sn; sv[i] = sn;
        }
      }
      emit_state(sh + (size_t)(1 + sel) * 32768, sw0, lane, mrow0, jb, sv);
      sig(chB_s);
    }
    // ---------- stage C: sel0: s3,s4 from s1 ; sel1: s5,s6 from s2 (mean-only) ----------
    ctr_wait(chB, 8u * ep);
    frag_gather(af, sh + (size_t)(1 + sel) * 32768, rowoff);
    {
      f32x4 a0 = {0, 0, 0, 0}, a1 = {0, 0, 0, 0};
#pragma unroll
      for (int kc = 0; kc < 16; ++kc) {
        u32x4 a = af[kc];
        a0 = mfma16(a, lw[(3 + 2 * sel) * 1024 + kc * 64 + lane], a0);
        a1 = mfma16(a, lw[(4 + 2 * sel) * 1024 + kc * 64 + lane], a1);
      }
      float p0[4], p1[4];
#pragma unroll
      for (int i = 0; i < 4; ++i) { p0[i] = __shfl_xor(a0[i], 8); p1[i] = __shfl_xor(a1[i], 8); }
      if (sel == 0) {
        float s3v[4], s4v[4];
        if (n < 8) {
#pragma unroll
          for (int i = 0; i < 4; ++i) {
            float sp = s1r[i];
            float s3 = sp + sigm(a0[i]) * (sigm(p0[i]) - sp);        // step2: sigmoid
            float s4 = sp + sigm(a1[i]) * (p1[i] - sp);              // step3: identity
            mean[i] += s3 + s4;
            s3r[i] = s3;
            s3v[i] = s3; s4v[i] = s4;
            scr_s4[sbase + i * 8] = s4;  // drained by the lgkm wait below
            sw0[(r0 + i) * 8 + (n & 7)] = f2h(s3);
            sw1[(r0 + i) * 8 + (n & 7)] = f2h(s4);
          }
        }
        asm volatile("s_waitcnt lgkmcnt(0)" ::: "memory");
        __builtin_amdgcn_sched_barrier(0);
        u32 w0v = ((const u32*)sw0)[lane];
        u32 w1v = ((const u32*)sw1)[lane];
        u16* a3 = sh + (size_t)3 * 32768 + (size_t)(mrow0 + (lane >> 2)) * 512 + jb * 8 + (lane & 3) * 2;
        u16* a4 = sh + (size_t)4 * 32768 + (size_t)(mrow0 + (lane >> 2)) * 512 + jb * 8 + (lane & 3) * 2;
        asm volatile("global_store_dword %0, %1, off sc0 sc1" :: "v"(a3), "v"(w0v) : "memory");
        asm volatile("global_store_dword %0, %1, off sc0 sc1" :: "v"(a4), "v"(w1v) : "memory");
        sig(chC_s);
      } else {
        if (n < 8) {
#pragma unroll
          for (int i = 0; i < 4; ++i) {
            float sp = s1r[i];
            float s5 = sp + sigm(a0[i]) * (tanhx(p0[i]) - sp);       // step4: tanh
            float s6 = sp + sigm(a1[i]) * (fmaxf(p1[i], 0.f) - sp);  // step5: relu
            mean[i] += s5 + s6;
          }
        }
      }
    }
    // ---------- stage D: sel0: s7 from s3 ; sel1: s8 from s4 ; h = mean/8 ----------
    ctr_wait(chC, 8u * ep);
    frag_gather(af, sh + (size_t)(3 + sel) * 32768, rowoff);
    {
      f32x4 acc = mm(af, lw, 7 + sel, lane);
      float part[4];
#pragma unroll
      for (int i = 0; i < 4; ++i) part[i] = __shfl_xor(acc[i], 8);
      if (sel == 1) {
        if (n < 8) {
#pragma unroll
          for (int i = 0; i < 4; ++i) {
            float sp = scr_s4[sbase + i * 8];
            float s8 = sp + sigm(acc[i]) * (part[i] - sp);           // step7: identity
            scr_m1[sbase + i * 8] = mean[i] + s8;
          }
        }
        asm volatile("s_waitcnt lgkmcnt(0)" ::: "memory");
        if (lane == 0)
          __hip_atomic_store(&lflag[mt], ep, __ATOMIC_RELAXED, __HIP_MEMORY_SCOPE_WORKGROUP);
      } else {
        while (__hip_atomic_load(&lflag[mt], __ATOMIC_RELAXED,
                                 __HIP_MEMORY_SCOPE_WORKGROUP) < ep) {}
        asm volatile("" ::: "memory");
        float hv[4];
        if (n < 8) {
#pragma unroll
          for (int i = 0; i < 4; ++i) {
            float s7 = s3r[i] + sigm(acc[i]) * (sigm(part[i]) - s3r[i]);  // step6: sigmoid
            float hn = (mean[i] + s7 + scr_m1[sbase + i * 8]) * 0.125f;
            h_reg[i] = hn; hv[i] = hn;
          }
        }
        emit_state(hh, sw0, lane, mrow0, jb, hv);
        sig(chD_s);
        // out[] stores AFTER the signal: off the critical D->A link (L2-cached)
        if (n < 8) {
#pragma unroll
          for (int i = 0; i < 4; ++i) {
            int m = mrow0 + r0 + i;
            out[((size_t)t * 64 + m) * 512 + jj] = hv[i];
            if (t == T_STEPS - 1) out[(size_t)T_STEPS * 64 * 512 + (size_t)m * 512 + jj] = hv[i];
          }
        }
      }
    }
  }
}

extern "C" void kernel_launch(void* const* d_in, const int* in_sizes, int n_in,
                              void* d_out, int out_size, void* d_ws, size_t ws_size,
                              hipStream_t stream) {
  const float* x_in = (const float*)d_in[0];  // [512,64,512] f32
  const float* h_in = (const float*)d_in[1];  // [1,64,512]  f32
  const float* w0   = (const float*)d_in[2];  // [1024,1024] f32
  const float* wsrc = (const float*)d_in[3];  // [8,512,1024] f32
  float* out = (float*)d_out;
  char* ws = (char*)d_ws;

  const size_t O_BAR = 0;                       // 16 KB counter region
  const size_t O_WP  = 16384;                   // 10 MB packed fp16 weights
  const size_t O_XWP = O_WP + 10485760;         // 64 MB packed XW (u64 frags)
  const size_t O_SH  = O_XWP + 67108864;        // s0..s4 fp16: 5 x 65536 B
  const size_t O_HH  = O_SH + 327680;           // h fp16
  const size_t NEED  = O_HH + 65536;            // ~74.5 MB
  if (ws_size < NEED) return;

  u32* bar = (u32*)(ws + O_BAR);
  u16* wp  = (u16*)(ws + O_WP);
  u64* xwp = (u64*)(ws + O_XWP);
  u16* sh  = (u16*)(ws + O_SH);
  u16* hh  = (u16*)(ws + O_HH);

  const int LDS_BYTES = 152592;  // weights 147456 + scr 3072 + scrw 2048 + lflag
  hipFuncSetAttribute((const void*)recur_kernel,
                      hipFuncAttributeMaxDynamicSharedMemorySize, LDS_BYTES);

  hipMemsetAsync(bar, 0, 16384, stream);  // zero all counters every call
  pack_kernel<<<dim3(2560), dim3(256), 0, stream>>>(w0, wsrc, wp);
  xw_kernel<<<dim3(8192), dim3(256), 0, stream>>>(x_in, wp, xwp);
  init_hh<<<dim3(128), dim3(256), 0, stream>>>(h_in, hh);
  recur_kernel<<<dim3(128), dim3(256), LDS_BYTES, stream>>>(xwp, h_in, wp, sh, hh, bar, out);
}